// Round 8
// baseline (28.919 us; speedup 1.0000x reference)
//
#include <hip/hip_runtime.h>

#define YDIM 30
#define PLANE2 32768            // 256*256/2 float2 per y-plane
#define NTHR 256
#define NBLK 1024               // 1024*256 threads * 2 px = 524288 pixels
#define NPIX 15728640.0         // 8*30*65536

__global__ __launch_bounds__(NTHR, 4) void drl_main(const float2* __restrict__ out,
                                                    float* __restrict__ partial) {
    const int g = blockIdx.x * NTHR + threadIdx.x;     // float2-group id
    const int b = g >> 15;                             // batch (32768 groups)
    const int hw2 = g & 32767;

    const float2* p0 = out + (size_t)b * (2 * YDIM * PLANE2) + hw2;  // out[b][0]
    const float2* p1 = p0 + YDIM * PLANE2;                            // out[b][1]

    // ---- pass 1: out0 scan with argmin-snapshot
    float run_s [2] = {0,0};
    float run_sx[2] = {0,0};
    float sn_s [2]  = {0,0};
    float sn_sx[2]  = {0,0};
    float best[2]   = {-7,-7};     // diff[0] = -DIST_IND
    float fd  [2]   = {0,0};
    float prev[2];

#pragma unroll
    for (int y = 0; y < YDIM; ++y) {
        float2 v = p0[y * PLANE2];
        float cur[2] = {v.x, v.y};
        if (y >= 2 && y <= YDIM - 2) {     // diff[1], diff[29] forced to 0 in ref
#pragma unroll
            for (int c = 0; c < 2; ++c) {
                float df = cur[c] - prev[c];
                bool lt = df < best[c];    // strict < = first-occurrence argmin
                best[c]  = lt ? df        : best[c];
                fd[c]    = lt ? (float)y  : fd[c];
                sn_s[c]  = lt ? run_s[c]  : sn_s[c];
                sn_sx[c] = lt ? run_sx[c] : sn_sx[c];
            }
        }
#pragma unroll
        for (int c = 0; c < 2; ++c) {
            run_s[c] += cur[c];
            run_sx[c] = fmaf((float)y, cur[c], run_sx[c]);
            prev[c]   = cur[c];
        }
    }

    // ---- prefetch ALL of out1 into registers BEFORE the divide chain, so the
    // fit-parameter latency (4 rcp chains) overlaps the pass-2 memory latency.
    // Fully unrolled, compile-time indices -> stays in VGPRs (60 regs).
    float2 pl[YDIM];
#pragma unroll
    for (int y = 0; y < YDIM; ++y) pl[y] = p1[y * PLANE2];

    // ---- fit parameters (reference quirks preserved)
    float sc_b[2], itc_b[2], sc_a[2], itc_a[2];
#pragma unroll
    for (int c = 0; c < 2; ++c) {
        float nb  = fd[c];
        float na  = (float)YDIM - nb;      // >= 2 always (d <= 28)
        float nsb = fmaxf(nb, 1.f);
        float Syb  = sn_s[c];
        float Sxyb = sn_sx[c];
        float Sya  = run_s[c] - Syb;
        float Sxya = fmaf(-nb, Sya, run_sx[c] - sn_sx[c]);  // Σ(y-d)c0, y>=d
        float mxb = nb * (nb - 1.f) * 0.5f / nsb;
        float myb = Syb / nsb;
        float mxa = (na - 1.f) * 0.5f;
        float mya = Sya / na;
        float covb = fmaf(-mxb, Syb, Sxyb);
        float cova = fmaf(-mxa, Sya, Sxya);
        float varb = nb * (nb * nb - 1.f) * (1.f / 12.f);
        float vara = na * (na * na - 1.f) * (1.f / 12.f);
        float slb = (varb > 0.f) ? covb / fmaxf(varb, 1.f) : 0.f;
        float sla = (vara > 0.f) ? cova / fmaxf(vara, 1.f) : 0.f;
        itc_b[c] = fminf(fmaxf(myb - slb * mxb, 0.f), 100.f);  // raw slope here
        itc_a[c] = fminf(fmaxf(mya - sla * mxa, 0.f), 100.f);
        sc_b[c]  = fminf(fmaxf(slb, 0.f), 2.f);                // clipped in fitted
        sc_a[c]  = fminf(fmaxf(sla, 0.f), 2.f);
    }

    // ---- pass 2: consume prefetched registers
    float acc[2] = {0,0};
#pragma unroll
    for (int y = 0; y < YDIM; ++y) {
        float t1[2] = {pl[y].x, pl[y].y};
#pragma unroll
        for (int c = 0; c < 2; ++c) {
            float xf  = (float)y;
            float fb  = fmaf(sc_b[c], xf,          itc_b[c]);
            float fa  = fmaf(sc_a[c], xf - fd[c],  itc_a[c]);
            float fit = (xf < fd[c]) ? fb : fa;    // mask_b = t < d
            float e   = fit - t1[c];
            acc[c]    = fmaf(e, e, acc[c]);
        }
    }
    float a = acc[0] + acc[1];

    // ---- block reduce, plain store of the block partial (no atomics)
#pragma unroll
    for (int off = 32; off > 0; off >>= 1) a += __shfl_down(a, off, 64);
    __shared__ float wsum[NTHR / 64];
    if ((threadIdx.x & 63) == 0) wsum[threadIdx.x >> 6] = a;
    __syncthreads();
    if (threadIdx.x == 0)
        partial[blockIdx.x] = (wsum[0] + wsum[1]) + (wsum[2] + wsum[3]);
}

// single-wave final reduction: fixed-order double accumulation + fixed shfl
// tree -> bitwise deterministic across launches.
__global__ __launch_bounds__(64) void drl_reduce(const float* __restrict__ partial,
                                                 float* __restrict__ outp) {
    const int t = threadIdx.x;           // one wave: 0..63
    double s = 0.0;
#pragma unroll
    for (int k = 0; k < NBLK / 64; ++k)  // 16 partials per lane, fixed order
        s += (double)partial[t + k * 64];
#pragma unroll
    for (int off = 32; off > 0; off >>= 1)
        s += __shfl_down(s, off, 64);    // fixed tree, deterministic
    if (t == 0) outp[0] = (float)(s / NPIX);
}

extern "C" void kernel_launch(void* const* d_in, const int* in_sizes, int n_in,
                              void* d_out, int out_size, void* d_ws, size_t ws_size,
                              hipStream_t stream) {
    const float2* out_t = (const float2*)d_in[0];   // (8,2,30,256,256) f32
    // d_in[1] = target: unused by the reference loss
    float* partial = (float*)d_ws;                  // NBLK floats, fully
                                                    // rewritten every launch
    float* loss    = (float*)d_out;

    drl_main<<<NBLK, NTHR, 0, stream>>>(out_t, partial);
    drl_reduce<<<1, 64, 0, stream>>>(partial, loss);
}

// Round 9
// 27.402 us; speedup vs baseline: 1.0554x; 1.0554x over previous
//
#include <hip/hip_runtime.h>

#define YDIM 30
#define PLANE4 16384            // 256*256/4 float4 per y-plane
#define NTHR 256
#define NBLK 512                // 512*256 threads * 4 px = 524288 pixels
#define NPIX 15728640.0         // 8*30*65536

__global__ __launch_bounds__(NTHR) void drl_main(const float4* __restrict__ out,
                                                 float* __restrict__ partial) {
    const int g = blockIdx.x * NTHR + threadIdx.x;     // float4-group id
    const int b = g >> 14;                             // batch
    const int hw4 = g & 16383;

    const float4* p0 = out + (size_t)b * (2 * YDIM * PLANE4) + hw4;  // out[b][0]
    const float4* p1 = p0 + YDIM * PLANE4;                            // out[b][1]

    // ---- pass 1: out0 scan with argmin-snapshot
    float run_s [4] = {0,0,0,0};
    float run_sx[4] = {0,0,0,0};
    float sn_s [4]  = {0,0,0,0};
    float sn_sx[4]  = {0,0,0,0};
    float best[4]   = {-7,-7,-7,-7};   // diff[0] = -DIST_IND
    float fd  [4]   = {0,0,0,0};
    float prev[4];

#pragma unroll
    for (int y = 0; y < YDIM; ++y) {
        float4 v = p0[y * PLANE4];
        float cur[4] = {v.x, v.y, v.z, v.w};
        if (y >= 2 && y <= YDIM - 2) {     // diff[1], diff[29] forced to 0 in ref
#pragma unroll
            for (int c = 0; c < 4; ++c) {
                float df = cur[c] - prev[c];
                bool lt = df < best[c];    // strict < = first-occurrence argmin
                best[c]  = lt ? df        : best[c];
                fd[c]    = lt ? (float)y  : fd[c];
                sn_s[c]  = lt ? run_s[c]  : sn_s[c];
                sn_sx[c] = lt ? run_sx[c] : sn_sx[c];
            }
        }
#pragma unroll
        for (int c = 0; c < 4; ++c) {
            run_s[c] += cur[c];
            run_sx[c] = fmaf((float)y, cur[c], run_sx[c]);
            prev[c]   = cur[c];
        }
    }

    // ---- fit parameters (reference quirks preserved)
    float sc_b[4], itc_b[4], sc_a[4], itc_a[4];
#pragma unroll
    for (int c = 0; c < 4; ++c) {
        float nb  = fd[c];
        float na  = (float)YDIM - nb;      // >= 2 always (d <= 28)
        float nsb = fmaxf(nb, 1.f);
        float Syb  = sn_s[c];
        float Sxyb = sn_sx[c];
        float Sya  = run_s[c] - Syb;
        float Sxya = fmaf(-nb, Sya, run_sx[c] - sn_sx[c]);  // Σ(y-d)c0, y>=d
        float mxb = nb * (nb - 1.f) * 0.5f / nsb;
        float myb = Syb / nsb;
        float mxa = (na - 1.f) * 0.5f;
        float mya = Sya / na;
        float covb = fmaf(-mxb, Syb, Sxyb);
        float cova = fmaf(-mxa, Sya, Sxya);
        float varb = nb * (nb * nb - 1.f) * (1.f / 12.f);
        float vara = na * (na * na - 1.f) * (1.f / 12.f);
        float slb = (varb > 0.f) ? covb / fmaxf(varb, 1.f) : 0.f;
        float sla = (vara > 0.f) ? cova / fmaxf(vara, 1.f) : 0.f;
        itc_b[c] = fminf(fmaxf(myb - slb * mxb, 0.f), 100.f);  // raw slope here
        itc_a[c] = fminf(fmaxf(mya - sla * mxa, 0.f), 100.f);
        sc_b[c]  = fminf(fmaxf(slb, 0.f), 2.f);                // clipped in fitted
        sc_a[c]  = fminf(fmaxf(sla, 0.f), 2.f);
    }

    // ---- pass 2: independent out1 stream
    float acc[4] = {0,0,0,0};
#pragma unroll
    for (int y = 0; y < YDIM; ++y) {
        float4 v = p1[y * PLANE4];
        float t1[4] = {v.x, v.y, v.z, v.w};
#pragma unroll
        for (int c = 0; c < 4; ++c) {
            float xf  = (float)y;
            float fb  = fmaf(sc_b[c], xf,          itc_b[c]);
            float fa  = fmaf(sc_a[c], xf - fd[c],  itc_a[c]);
            float fit = (xf < fd[c]) ? fb : fa;    // mask_b = t < d
            float e   = fit - t1[c];
            acc[c]    = fmaf(e, e, acc[c]);
        }
    }
    float a = (acc[0] + acc[1]) + (acc[2] + acc[3]);

    // ---- block reduce, plain store of the block partial (no atomics)
#pragma unroll
    for (int off = 32; off > 0; off >>= 1) a += __shfl_down(a, off, 64);
    __shared__ float wsum[NTHR / 64];
    if ((threadIdx.x & 63) == 0) wsum[threadIdx.x >> 6] = a;
    __syncthreads();
    if (threadIdx.x == 0)
        partial[blockIdx.x] = (wsum[0] + wsum[1]) + (wsum[2] + wsum[3]);
}

// single-wave final reduction: fixed-order double accumulation + fixed shfl
// tree -> bitwise deterministic across launches.
__global__ __launch_bounds__(64) void drl_reduce(const float* __restrict__ partial,
                                                 float* __restrict__ outp) {
    const int t = threadIdx.x;           // one wave: 0..63
    double s = 0.0;
#pragma unroll
    for (int k = 0; k < NBLK / 64; ++k)  // 8 partials per lane, fixed order
        s += (double)partial[t + k * 64];
#pragma unroll
    for (int off = 32; off > 0; off >>= 1)
        s += __shfl_down(s, off, 64);    // fixed tree, deterministic
    if (t == 0) outp[0] = (float)(s / NPIX);
}

extern "C" void kernel_launch(void* const* d_in, const int* in_sizes, int n_in,
                              void* d_out, int out_size, void* d_ws, size_t ws_size,
                              hipStream_t stream) {
    const float4* out_t = (const float4*)d_in[0];   // (8,2,30,256,256) f32
    // d_in[1] = target: unused by the reference loss
    float* partial = (float*)d_ws;                  // NBLK floats, fully
                                                    // rewritten every launch
    float* loss    = (float*)d_out;

    drl_main<<<NBLK, NTHR, 0, stream>>>(out_t, partial);
    drl_reduce<<<1, 64, 0, stream>>>(partial, loss);
}